// Round 2
// baseline (1723.373 us; speedup 1.0000x reference)
//
#include <hip/hip_runtime.h>
#include <hip/hip_bf16.h>

typedef _Float16 half8 __attribute__((ext_vector_type(8)));
typedef float floatx4 __attribute__((ext_vector_type(4)));

// ---------------------------------------------------------------------------
// async global->LDS, 16B per lane (wave-uniform LDS base + lane*16)
__device__ inline void gload_lds16(const void* g, void* l) {
  __builtin_amdgcn_global_load_lds(
      (const __attribute__((address_space(1))) unsigned int*)g,
      (__attribute__((address_space(3))) unsigned int*)l, 16, 0, 0);
}

// ---------------------------------------------------------------------------
// gates[n][e] = softmax_e( x[n] . gate_w[e] + gate_b[e] )   (one wave per row)
__global__ __launch_bounds__(256) void gates_kernel(
    const float* __restrict__ x, const float* __restrict__ gw,
    const float* __restrict__ gb, float* __restrict__ gates) {
  const int lane = threadIdx.x & 63, wid = threadIdx.x >> 6;
  const int n = blockIdx.x * 4 + wid;
  const float* xr = x + (size_t)n * 1024;
  float xv[16];
#pragma unroll
  for (int i = 0; i < 16; ++i) xv[i] = xr[lane + i * 64];
  float logit[8];
#pragma unroll
  for (int e = 0; e < 8; ++e) {
    const float* wr = gw + (size_t)e * 1024;
    float p = 0.f;
#pragma unroll
    for (int i = 0; i < 16; ++i) p += xv[i] * wr[lane + i * 64];
#pragma unroll
    for (int off = 32; off > 0; off >>= 1) p += __shfl_xor(p, off);
    logit[e] = p + gb[e];
  }
  float mx = logit[0];
#pragma unroll
  for (int e = 1; e < 8; ++e) mx = fmaxf(mx, logit[e]);
  float s = 0.f;
#pragma unroll
  for (int e = 0; e < 8; ++e) { logit[e] = expf(logit[e] - mx); s += logit[e]; }
  if (lane < 8) gates[(size_t)n * 8 + lane] = logit[lane] / s;
}

// ---------------------------------------------------------------------------
// out[n][d] = sum_e gates[n][e] * b2[e][d]   (also erases the 0xAA poison;
// GEMM2 then atomicAdds the matmul term on top)
__global__ __launch_bounds__(256) void bias_init_kernel(
    const float* __restrict__ gates, const float* __restrict__ b2,
    float* __restrict__ out) {
  const int idx = blockIdx.x * 256 + threadIdx.x;  // one float4 per thread
  const int n = idx >> 8;          // D/4 = 256 float4 per row
  const int d = (idx & 255) << 2;
  const float* g = gates + (size_t)n * 8;
  floatx4 acc = {0.f, 0.f, 0.f, 0.f};
#pragma unroll
  for (int e = 0; e < 8; ++e) {
    const float ge = g[e];
    const floatx4 b = *(const floatx4*)(b2 + (size_t)e * 1024 + d);
#pragma unroll
    for (int j = 0; j < 4; ++j) acc[j] += ge * b[j];
  }
  *(floatx4*)(out + (size_t)n * 1024 + d) = acc;
}

// ---------------------------------------------------------------------------
// fp32 -> fp16 bulk convert (8 elements/thread)
__global__ __launch_bounds__(256) void cvt_f32_f16_kernel(
    const float* __restrict__ in, _Float16* __restrict__ out, int n8) {
  const int i = blockIdx.x * 256 + threadIdx.x;
  if (i >= n8) return;
  const float4* p = (const float4*)(in + (size_t)i * 8);
  float4 a = p[0], b = p[1];
  half8 h;
  h[0] = (_Float16)a.x; h[1] = (_Float16)a.y; h[2] = (_Float16)a.z; h[3] = (_Float16)a.w;
  h[4] = (_Float16)b.x; h[5] = (_Float16)b.y; h[6] = (_Float16)b.z; h[7] = (_Float16)b.w;
  *(half8*)(out + (size_t)i * 8) = h;
}

// ---------------------------------------------------------------------------
// out[c][r] = (fp16) in[r][c]   — tiled transpose+convert, in: [R][C] fp32
__global__ __launch_bounds__(256) void transpose_cvt_kernel(
    const float* __restrict__ in, _Float16* __restrict__ out, int R, int C) {
  __shared__ _Float16 tile[32][33];
  const int tx = threadIdx.x & 31, ty = threadIdx.x >> 5;
  const int c0 = blockIdx.x << 5, r0 = blockIdx.y << 5;
#pragma unroll
  for (int i = 0; i < 4; ++i)
    tile[ty + i * 8][tx] = (_Float16)in[(size_t)(r0 + ty + i * 8) * C + c0 + tx];
  __syncthreads();
#pragma unroll
  for (int i = 0; i < 4; ++i)
    out[(size_t)(c0 + ty + i * 8) * R + r0 + tx] = tile[tx][ty + i * 8];
}

// ---------------------------------------------------------------------------
// 128x128-tile f16 MFMA GEMM, C = A[M][lda] * Bt[Nn][ldb]^T over k-chunk
// kLen starting at blockIdx.z*kLen.
// EPI 0: Hout = relu(acc + bias)                  (fp16 store)
// EPI 1: atomicAdd(Out, gates[n][e] * acc)        (fp32; bias handled upstream)
template <int EPI>
__global__ __launch_bounds__(256, 2) void gemm_kernel(
    const _Float16* __restrict__ A, const _Float16* __restrict__ Bt,
    const float* __restrict__ bias, const float* __restrict__ gates, int e,
    _Float16* __restrict__ Hout, float* __restrict__ Out, int M, int Nn,
    int lda, int ldb, int kLen) {
  __shared__ _Float16 As[2][128 * 32];
  __shared__ _Float16 Bs[2][128 * 32];
  const int tid = threadIdx.x;
  const int lane = tid & 63;
  const int wid = tid >> 6;
  const int wr = wid >> 1, wc = wid & 1;  // 2x2 waves, 64x64 each
  const int m0 = blockIdx.x * 128, n0 = blockIdx.y * 128;
  const int kb = blockIdx.z * kLen;

  floatx4 acc[4][4] = {};

  auto stage = [&](int buf, int kt) {
    const int k0 = kb + (kt << 5);
#pragma unroll
    for (int it = 0; it < 2; ++it) {
      const int s = tid + it * 256;  // 512 slots of 8 halves; A row-major [128][32]
      gload_lds16(A + (size_t)(m0 + (s >> 2)) * lda + k0 + (s & 3) * 8,
                  &As[buf][s * 8]);
    }
#pragma unroll
    for (int it = 0; it < 2; ++it) {
      const int s = tid + it * 256;  // Bt tile [128 cols][32 k]
      gload_lds16(Bt + (size_t)(n0 + (s >> 2)) * ldb + k0 + (s & 3) * 8,
                  &Bs[buf][s * 8]);
    }
  };

  const int nk = kLen >> 5;
  stage(0, 0);
  __syncthreads();

  for (int kt = 0; kt < nk; ++kt) {
    const int cur = kt & 1;
    if (kt + 1 < nk) stage(cur ^ 1, kt + 1);
    const int krow = (lane >> 4) * 8;  // k-octet per lane-quad
    half8 af[4], bfr[4];
#pragma unroll
    for (int m = 0; m < 4; ++m) {
      const int row = wr * 64 + m * 16 + (lane & 15);
      af[m] = *(const half8*)&As[cur][row * 32 + krow];
    }
#pragma unroll
    for (int n = 0; n < 4; ++n) {
      const int row = wc * 64 + n * 16 + (lane & 15);
      bfr[n] = *(const half8*)&Bs[cur][row * 32 + krow];
    }
#pragma unroll
    for (int m = 0; m < 4; ++m)
#pragma unroll
      for (int n = 0; n < 4; ++n)
        acc[m][n] =
            __builtin_amdgcn_mfma_f32_16x16x32_f16(af[m], bfr[n], acc[m][n], 0, 0, 0);
    __syncthreads();  // compiler drains vmcnt+lgkmcnt here: dbuf safe
  }

  // epilogue: D-fragment col = lane&15, row = (lane>>4)*4 + r
#pragma unroll
  for (int m = 0; m < 4; ++m) {
    const int gr0 = m0 + wr * 64 + m * 16 + ((lane >> 4) << 2);
#pragma unroll
    for (int n = 0; n < 4; ++n) {
      const int gc = n0 + wc * 64 + n * 16 + (lane & 15);
#pragma unroll
      for (int r = 0; r < 4; ++r) {
        const int gr = gr0 + r;
        if (EPI == 0) {
          const float v = acc[m][n][r] + bias[gc];
          Hout[(size_t)gr * Nn + gc] = (_Float16)fmaxf(v, 0.0f);
        } else {
          const float g = gates[(size_t)gr * 8 + e];
          atomicAdd(Out + (size_t)gr * Nn + gc, g * acc[m][n][r]);
        }
      }
    }
  }
}

// ---------------------------------------------------------------------------
extern "C" void kernel_launch(void* const* d_in, const int* in_sizes, int n_in,
                              void* d_out, int out_size, void* d_ws,
                              size_t ws_size, hipStream_t stream) {
  const float* x  = (const float*)d_in[0];
  const float* gw = (const float*)d_in[1];
  const float* gb = (const float*)d_in[2];
  const float* w1 = (const float*)d_in[3];
  const float* b1 = (const float*)d_in[4];
  const float* w2 = (const float*)d_in[5];
  const float* b2 = (const float*)d_in[6];
  float* out = (float*)d_out;

  const int N = 8192, D = 1024, H = 4096, E = 8;

  char* ws = (char*)d_ws;
  float* gates   = (float*)ws;                                     // 256 KB
  _Float16* x_h  = (_Float16*)(ws + (1ull << 20));                 // 16 MB
  _Float16* w1t  = (_Float16*)(ws + (1ull << 20) + (16ull << 20)); // 8 MB  [H][D]
  _Float16* w2t  = (_Float16*)(ws + (1ull << 20) + (24ull << 20)); // 8 MB  [D][H]
  _Float16* Hbuf = (_Float16*)(ws + (1ull << 20) + (32ull << 20)); // 64 MB [N][H]

  gates_kernel<<<N / 4, 256, 0, stream>>>(x, gw, gb, gates);
  bias_init_kernel<<<N * D / 4 / 256, 256, 0, stream>>>(gates, b2, out);
  cvt_f32_f16_kernel<<<(N * D / 8 + 255) / 256, 256, 0, stream>>>(x, x_h, N * D / 8);

  for (int e = 0; e < E; ++e) {
    // w1[e]: [D][H] -> w1t [H][D];  w2[e]: [H][D] -> w2t [D][H]
    transpose_cvt_kernel<<<dim3(H / 32, D / 32), 256, 0, stream>>>(
        w1 + (size_t)e * D * H, w1t, D, H);
    transpose_cvt_kernel<<<dim3(D / 32, H / 32), 256, 0, stream>>>(
        w2 + (size_t)e * H * D, w2t, H, D);
    // GEMM1: [N,D] x [H,D]^T -> relu(+b1) -> Hbuf [N,H] fp16
    gemm_kernel<0><<<dim3(N / 128, H / 128, 1), 256, 0, stream>>>(
        x_h, w1t, b1 + (size_t)e * H, nullptr, e, Hbuf, nullptr, N, H, D, D, D);
    // GEMM2: [N,H] x [D,H]^T, split-K x2, atomic gated accumulate into out
    gemm_kernel<1><<<dim3(N / 128, D / 128, 2), 256, 0, stream>>>(
        Hbuf, w2t, nullptr, gates, e, nullptr, out, N, D, H, H, H / 2);
  }
}

// Round 3
// 1589.009 us; speedup vs baseline: 1.0846x; 1.0846x over previous
//
#include <hip/hip_runtime.h>
#include <hip/hip_bf16.h>

typedef _Float16 half8 __attribute__((ext_vector_type(8)));
typedef float floatx4 __attribute__((ext_vector_type(4)));

// ---------------------------------------------------------------------------
// async global->LDS, 16B per lane (wave-uniform LDS base + lane*16)
__device__ inline void gload_lds16(const void* g, void* l) {
  __builtin_amdgcn_global_load_lds(
      (const __attribute__((address_space(1))) unsigned int*)g,
      (__attribute__((address_space(3))) unsigned int*)l, 16, 0, 0);
}

#define BAR()    asm volatile("s_barrier" ::: "memory")
#define WAITL0() asm volatile("s_waitcnt lgkmcnt(0)" ::: "memory")
#define WAITV2() asm volatile("s_waitcnt vmcnt(2)" ::: "memory")

// ---------------------------------------------------------------------------
// gates[n][e] = softmax_e( x[n] . gate_w[e] + gate_b[e] )   (one wave per row)
__global__ __launch_bounds__(256) void gates_kernel(
    const float* __restrict__ x, const float* __restrict__ gw,
    const float* __restrict__ gb, float* __restrict__ gates) {
  const int lane = threadIdx.x & 63, wid = threadIdx.x >> 6;
  const int n = blockIdx.x * 4 + wid;
  const float* xr = x + (size_t)n * 1024;
  float xv[16];
#pragma unroll
  for (int i = 0; i < 16; ++i) xv[i] = xr[lane + i * 64];
  float logit[8];
#pragma unroll
  for (int e = 0; e < 8; ++e) {
    const float* wr = gw + (size_t)e * 1024;
    float p = 0.f;
#pragma unroll
    for (int i = 0; i < 16; ++i) p += xv[i] * wr[lane + i * 64];
#pragma unroll
    for (int off = 32; off > 0; off >>= 1) p += __shfl_xor(p, off);
    logit[e] = p + gb[e];
  }
  float mx = logit[0];
#pragma unroll
  for (int e = 1; e < 8; ++e) mx = fmaxf(mx, logit[e]);
  float s = 0.f;
#pragma unroll
  for (int e = 0; e < 8; ++e) { logit[e] = expf(logit[e] - mx); s += logit[e]; }
  if (lane < 8) gates[(size_t)n * 8 + lane] = logit[lane] / s;
}

// ---------------------------------------------------------------------------
// out[n][d] = sum_e gates[n][e] * b2[e][d]   (erases poison; GEMM2 atomicAdds)
__global__ __launch_bounds__(256) void bias_init_kernel(
    const float* __restrict__ gates, const float* __restrict__ b2,
    float* __restrict__ out) {
  const int idx = blockIdx.x * 256 + threadIdx.x;
  const int n = idx >> 8;
  const int d = (idx & 255) << 2;
  const float* g = gates + (size_t)n * 8;
  floatx4 acc = {0.f, 0.f, 0.f, 0.f};
#pragma unroll
  for (int e = 0; e < 8; ++e) {
    const float ge = g[e];
    const floatx4 b = *(const floatx4*)(b2 + (size_t)e * 1024 + d);
#pragma unroll
    for (int j = 0; j < 4; ++j) acc[j] += ge * b[j];
  }
  *(floatx4*)(out + (size_t)n * 1024 + d) = acc;
}

// ---------------------------------------------------------------------------
__global__ __launch_bounds__(256) void cvt_f32_f16_kernel(
    const float* __restrict__ in, _Float16* __restrict__ out, int n8) {
  const int i = blockIdx.x * 256 + threadIdx.x;
  if (i >= n8) return;
  const float4* p = (const float4*)(in + (size_t)i * 8);
  float4 a = p[0], b = p[1];
  half8 h;
  h[0] = (_Float16)a.x; h[1] = (_Float16)a.y; h[2] = (_Float16)a.z; h[3] = (_Float16)a.w;
  h[4] = (_Float16)b.x; h[5] = (_Float16)b.y; h[6] = (_Float16)b.z; h[7] = (_Float16)b.w;
  *(half8*)(out + (size_t)i * 8) = h;
}

// ---------------------------------------------------------------------------
__global__ __launch_bounds__(256) void transpose_cvt_kernel(
    const float* __restrict__ in, _Float16* __restrict__ out, int R, int C) {
  __shared__ _Float16 tile[32][33];
  const int tx = threadIdx.x & 31, ty = threadIdx.x >> 5;
  const int c0 = blockIdx.x << 5, r0 = blockIdx.y << 5;
#pragma unroll
  for (int i = 0; i < 4; ++i)
    tile[ty + i * 8][tx] = (_Float16)in[(size_t)(r0 + ty + i * 8) * C + c0 + tx];
  __syncthreads();
#pragma unroll
  for (int i = 0; i < 4; ++i)
    out[(size_t)(c0 + ty + i * 8) * R + r0 + tx] = tile[tx][ty + i * 8];
}

// ---------------------------------------------------------------------------
// 256x256-tile, BK=64, 8-phase pipelined f16 MFMA GEMM (T1+T2+T3+T4+T5).
//   C = A[M][lda] * Bt[Nn][ldb]^T over k in [kb, kb+kLen)
// 8 waves as 2(M)x4(N); per-wave output 128x64; LDS 128KB =
// 2 buf x {A0,A1,B0,B1} 16KB half-tiles, XOR-swizzled content
// (linear gload_lds dest + inverse-swizzled global source; swizzled reads).
// Stage schedule: tile T halves at (T-2).P4 [A0] and (T-1).P1-P3 [A1,B0,B1];
// one counted vmcnt(2) gate per tile at P4 (never drains to 0).
// EPI 0: Hout = relu(acc + bias)  fp16.   EPI 1: atomicAdd(Out, gate*acc).
template <int EPI>
__global__ __launch_bounds__(512, 2) void gemm256_kernel(
    const _Float16* __restrict__ A, const _Float16* __restrict__ Bt,
    const float* __restrict__ bias, const float* __restrict__ gates, int e,
    _Float16* __restrict__ Hout, float* __restrict__ Out, int lda, int ldb,
    int kLen, int Nout) {
  __shared__ _Float16 smem[2][4][8192];  // [buf][A0,A1,B0,B1][16KB]
  const int tid = threadIdx.x, lane = tid & 63, wid = tid >> 6;
  const int wm = wid >> 2, wn = wid & 3;

  // T1: bijective XCD swizzle on the xy-plane (nxy % 8 == 0 always here)
  const int gx = gridDim.x, nxy = gx * gridDim.y;
  const int f = blockIdx.x + gx * blockIdx.y;
  const int sw = (f & 7) * (nxy >> 3) + (f >> 3);
  const int m0 = (sw % gx) * 256, n0 = (sw / gx) * 256;
  const int kb = blockIdx.z * kLen;
  const int NT = kLen >> 6;

  floatx4 acc[8][4] = {};

  auto stage_half = [&](int h) {
    if (h >= 4 * NT) return;
    const int th = h >> 2, j = h & 3, bf = th & 1;
    const int k0 = kb + th * 64;
    const char* gb; int ld, rorig;
    if (j < 2) { gb = (const char*)A;  ld = lda; rorig = m0 + j * 128; }
    else       { gb = (const char*)Bt; ld = ldb; rorig = n0 + (j - 2) * 128; }
    _Float16* lb = &smem[bf][j][0];
#pragma unroll
    for (int i = 0; i < 2; ++i) {
      const int row = (wid * 2 + i) * 8 + (lane >> 3);
      const int gkb = ((lane & 7) * 16) ^ ((row & 7) << 4);  // inverse swizzle
      gload_lds16(gb + ((size_t)(rorig + row) * ld + k0) * 2 + gkb,
                  lb + (wid * 2 + i) * 512 + lane * 8);
    }
  };
  // T2-swizzled fragment reads (2-way bank aliasing = free)
  auto ldA = [&](int bf, int mf, int ks) -> half8 {
    const int row = mf * 16 + (lane & 15);
    const int kb2 = (ks * 64 + ((lane >> 4) << 4)) ^ ((row & 7) << 4);
    return *(const half8*)&smem[bf][wm][(row * 128 + kb2) >> 1];
  };
  auto ldB = [&](int bf, int nf, int ks) -> half8 {
    const int c = wn * 64 + nf * 16 + (lane & 15);
    const int r = c & 127;
    const int kb2 = (ks * 64 + ((lane >> 4) << 4)) ^ ((r & 7) << 4);
    return *(const half8*)&smem[bf][2 + (c >> 7)][(r * 128 + kb2) >> 1];
  };

  // prologue: tile0 fully + tile1.A0; keep tile1.A0 in flight
  for (int h = 0; h < 5; ++h) stage_half(h);
  WAITV2();
  BAR();

#pragma unroll 1
  for (int t = 0; t < NT; ++t) {
    const int bf = t & 1;
    half8 a[4][2], bh[2][2], bl[2][2];
    // ---- P1: read A m0-3 + B n2-3; stage (t+1).A1; MFMA Q(m0-3 x n2-3)
#pragma unroll
    for (int ks = 0; ks < 2; ++ks) {
#pragma unroll
      for (int m = 0; m < 4; ++m) a[m][ks] = ldA(bf, m, ks);
#pragma unroll
      for (int n = 0; n < 2; ++n) bh[n][ks] = ldB(bf, 2 + n, ks);
    }
    stage_half(4 * (t + 1) + 1);
    BAR(); WAITL0(); __builtin_amdgcn_sched_barrier(0);
    __builtin_amdgcn_s_setprio(1);
#pragma unroll
    for (int m = 0; m < 4; ++m)
#pragma unroll
      for (int n = 0; n < 2; ++n)
#pragma unroll
        for (int ks = 0; ks < 2; ++ks)
          acc[m][2 + n] = __builtin_amdgcn_mfma_f32_16x16x32_f16(
              a[m][ks], bh[n][ks], acc[m][2 + n], 0, 0, 0);
    __builtin_amdgcn_s_setprio(0);
    BAR();
    // ---- P2: read B n0-1; stage (t+1).B0; MFMA Q(m0-3 x n0-1)
#pragma unroll
    for (int ks = 0; ks < 2; ++ks)
#pragma unroll
      for (int n = 0; n < 2; ++n) bl[n][ks] = ldB(bf, n, ks);
    stage_half(4 * (t + 1) + 2);
    BAR(); WAITL0(); __builtin_amdgcn_sched_barrier(0);
    __builtin_amdgcn_s_setprio(1);
#pragma unroll
    for (int m = 0; m < 4; ++m)
#pragma unroll
      for (int n = 0; n < 2; ++n)
#pragma unroll
        for (int ks = 0; ks < 2; ++ks)
          acc[m][n] = __builtin_amdgcn_mfma_f32_16x16x32_f16(
              a[m][ks], bl[n][ks], acc[m][n], 0, 0, 0);
    __builtin_amdgcn_s_setprio(0);
    BAR();
    // ---- P3: read A m4-7; stage (t+1).B1; MFMA Q(m4-7 x n2-3)
#pragma unroll
    for (int ks = 0; ks < 2; ++ks)
#pragma unroll
      for (int m = 0; m < 4; ++m) a[m][ks] = ldA(bf, 4 + m, ks);
    stage_half(4 * (t + 1) + 3);
    BAR(); WAITL0(); __builtin_amdgcn_sched_barrier(0);
    __builtin_amdgcn_s_setprio(1);
#pragma unroll
    for (int m = 0; m < 4; ++m)
#pragma unroll
      for (int n = 0; n < 2; ++n)
#pragma unroll
        for (int ks = 0; ks < 2; ++ks)
          acc[4 + m][2 + n] = __builtin_amdgcn_mfma_f32_16x16x32_f16(
              a[m][ks], bh[n][ks], acc[4 + m][2 + n], 0, 0, 0);
    __builtin_amdgcn_s_setprio(0);
    BAR();
    // ---- P4: stage (t+2).A0 (region free after P3); gate vmcnt(2);
    //          MFMA Q(m4-7 x n0-1)
    stage_half(4 * (t + 2) + 0);
    WAITV2();
    BAR();
    __builtin_amdgcn_s_setprio(1);
#pragma unroll
    for (int m = 0; m < 4; ++m)
#pragma unroll
      for (int n = 0; n < 2; ++n)
#pragma unroll
        for (int ks = 0; ks < 2; ++ks)
          acc[4 + m][n] = __builtin_amdgcn_mfma_f32_16x16x32_f16(
              a[m][ks], bl[n][ks], acc[4 + m][n], 0, 0, 0);
    __builtin_amdgcn_s_setprio(0);
    BAR();
  }

  // epilogue: D-frag col = lane&15, row = (lane>>4)*4 + r
#pragma unroll
  for (int mf = 0; mf < 8; ++mf) {
    const int gr0 = m0 + wm * 128 + mf * 16 + ((lane >> 4) << 2);
#pragma unroll
    for (int nf = 0; nf < 4; ++nf) {
      const int gc = n0 + wn * 64 + nf * 16 + (lane & 15);
#pragma unroll
      for (int r = 0; r < 4; ++r) {
        const int gr = gr0 + r;
        if (EPI == 0) {
          const float v = acc[mf][nf][r] + bias[gc];
          Hout[(size_t)gr * Nout + gc] = (_Float16)fmaxf(v, 0.0f);
        } else {
          atomicAdd(Out + (size_t)gr * Nout + gc,
                    gates[(size_t)gr * 8 + e] * acc[mf][nf][r]);
        }
      }
    }
  }
}

// ---------------------------------------------------------------------------
extern "C" void kernel_launch(void* const* d_in, const int* in_sizes, int n_in,
                              void* d_out, int out_size, void* d_ws,
                              size_t ws_size, hipStream_t stream) {
  const float* x  = (const float*)d_in[0];
  const float* gw = (const float*)d_in[1];
  const float* gb = (const float*)d_in[2];
  const float* w1 = (const float*)d_in[3];
  const float* b1 = (const float*)d_in[4];
  const float* w2 = (const float*)d_in[5];
  const float* b2 = (const float*)d_in[6];
  float* out = (float*)d_out;

  const int N = 8192, D = 1024, H = 4096, E = 8;

  char* ws = (char*)d_ws;
  float* gates   = (float*)ws;                                     // 256 KB
  _Float16* x_h  = (_Float16*)(ws + (1ull << 20));                 // 16 MB
  _Float16* w1t  = (_Float16*)(ws + (1ull << 20) + (16ull << 20)); // 8 MB  [H][D]
  _Float16* w2t  = (_Float16*)(ws + (1ull << 20) + (24ull << 20)); // 8 MB  [D][H]
  _Float16* Hbuf = (_Float16*)(ws + (1ull << 20) + (32ull << 20)); // 64 MB [N][H]

  gates_kernel<<<N / 4, 256, 0, stream>>>(x, gw, gb, gates);
  bias_init_kernel<<<N * D / 4 / 256, 256, 0, stream>>>(gates, b2, out);
  cvt_f32_f16_kernel<<<(N * D / 8 + 255) / 256, 256, 0, stream>>>(x, x_h, N * D / 8);

  for (int e = 0; e < E; ++e) {
    transpose_cvt_kernel<<<dim3(H / 32, D / 32), 256, 0, stream>>>(
        w1 + (size_t)e * D * H, w1t, D, H);
    transpose_cvt_kernel<<<dim3(D / 32, H / 32), 256, 0, stream>>>(
        w2 + (size_t)e * H * D, w2t, H, D);
    // GEMM1: [8192,1024] x [4096,1024]^T -> relu(+b1) -> Hbuf fp16 [N][H]
    gemm256_kernel<0><<<dim3(N / 256, H / 256, 1), 512, 0, stream>>>(
        x_h, w1t, b1 + (size_t)e * H, nullptr, e, Hbuf, nullptr, D, D, D, H);
    // GEMM2: [8192,4096] x [1024,4096]^T, split-K x2, gated atomic accumulate
    gemm256_kernel<1><<<dim3(N / 256, D / 256, 2), 512, 0, stream>>>(
        Hbuf, w2t, nullptr, gates, e, nullptr, out, H, H, H / 2, D);
  }
}

// Round 4
// 1555.409 us; speedup vs baseline: 1.1080x; 1.0216x over previous
//
#include <hip/hip_runtime.h>
#include <hip/hip_bf16.h>

typedef _Float16 half8 __attribute__((ext_vector_type(8)));
typedef float floatx4 __attribute__((ext_vector_type(4)));

// ---------------------------------------------------------------------------
// async global->LDS, 16B per lane (wave-uniform LDS base + lane*16)
__device__ inline void gload_lds16(const void* g, void* l) {
  __builtin_amdgcn_global_load_lds(
      (const __attribute__((address_space(1))) unsigned int*)g,
      (__attribute__((address_space(3))) unsigned int*)l, 16, 0, 0);
}

// NOTE: no "memory" clobbers — a memory clobber makes the waitcnt-insertion
// pass drain vmcnt(0)+lgkmcnt(0) before the asm/barrier, defeating the
// counted-vmcnt pipeline (round-3 lesson: MfmaUtil stuck at 24%).
#define BARB()   __builtin_amdgcn_s_barrier()
#define WAITL0() asm volatile("s_waitcnt lgkmcnt(0)")
#define WAITV(n) asm volatile("s_waitcnt vmcnt(" #n ")")
#define SCHED0() __builtin_amdgcn_sched_barrier(0)

// ---------------------------------------------------------------------------
// gates[n][e] = softmax_e( x[n] . gate_w[e] + gate_b[e] )   (one wave per row)
__global__ __launch_bounds__(256) void gates_kernel(
    const float* __restrict__ x, const float* __restrict__ gw,
    const float* __restrict__ gb, float* __restrict__ gates) {
  const int lane = threadIdx.x & 63, wid = threadIdx.x >> 6;
  const int n = blockIdx.x * 4 + wid;
  const float* xr = x + (size_t)n * 1024;
  float xv[16];
#pragma unroll
  for (int i = 0; i < 16; ++i) xv[i] = xr[lane + i * 64];
  float logit[8];
#pragma unroll
  for (int e = 0; e < 8; ++e) {
    const float* wr = gw + (size_t)e * 1024;
    float p = 0.f;
#pragma unroll
    for (int i = 0; i < 16; ++i) p += xv[i] * wr[lane + i * 64];
#pragma unroll
    for (int off = 32; off > 0; off >>= 1) p += __shfl_xor(p, off);
    logit[e] = p + gb[e];
  }
  float mx = logit[0];
#pragma unroll
  for (int e = 1; e < 8; ++e) mx = fmaxf(mx, logit[e]);
  float s = 0.f;
#pragma unroll
  for (int e = 0; e < 8; ++e) { logit[e] = expf(logit[e] - mx); s += logit[e]; }
  if (lane < 8) gates[(size_t)n * 8 + lane] = logit[lane] / s;
}

// ---------------------------------------------------------------------------
// out[n][d] = sum_e gates[n][e] * b2[e][d]   (erases poison; GEMM2 atomicAdds)
__global__ __launch_bounds__(256) void bias_init_kernel(
    const float* __restrict__ gates, const float* __restrict__ b2,
    float* __restrict__ out) {
  const int idx = blockIdx.x * 256 + threadIdx.x;
  const int n = idx >> 8;
  const int d = (idx & 255) << 2;
  const float* g = gates + (size_t)n * 8;
  floatx4 acc = {0.f, 0.f, 0.f, 0.f};
#pragma unroll
  for (int e = 0; e < 8; ++e) {
    const float ge = g[e];
    const floatx4 b = *(const floatx4*)(b2 + (size_t)e * 1024 + d);
#pragma unroll
    for (int j = 0; j < 4; ++j) acc[j] += ge * b[j];
  }
  *(floatx4*)(out + (size_t)n * 1024 + d) = acc;
}

// ---------------------------------------------------------------------------
__global__ __launch_bounds__(256) void cvt_f32_f16_kernel(
    const float* __restrict__ in, _Float16* __restrict__ out, int n8) {
  const int i = blockIdx.x * 256 + threadIdx.x;
  if (i >= n8) return;
  const float4* p = (const float4*)(in + (size_t)i * 8);
  float4 a = p[0], b = p[1];
  half8 h;
  h[0] = (_Float16)a.x; h[1] = (_Float16)a.y; h[2] = (_Float16)a.z; h[3] = (_Float16)a.w;
  h[4] = (_Float16)b.x; h[5] = (_Float16)b.y; h[6] = (_Float16)b.z; h[7] = (_Float16)b.w;
  *(half8*)(out + (size_t)i * 8) = h;
}

// ---------------------------------------------------------------------------
__global__ __launch_bounds__(256) void transpose_cvt_kernel(
    const float* __restrict__ in, _Float16* __restrict__ out, int R, int C) {
  __shared__ _Float16 tile[32][33];
  const int tx = threadIdx.x & 31, ty = threadIdx.x >> 5;
  const int c0 = blockIdx.x << 5, r0 = blockIdx.y << 5;
#pragma unroll
  for (int i = 0; i < 4; ++i)
    tile[ty + i * 8][tx] = (_Float16)in[(size_t)(r0 + ty + i * 8) * C + c0 + tx];
  __syncthreads();
#pragma unroll
  for (int i = 0; i < 4; ++i)
    out[(size_t)(c0 + ty + i * 8) * R + r0 + tx] = tile[tx][ty + i * 8];
}

// ---------------------------------------------------------------------------
// 256x256-tile, BK=64, 8-phase pipelined f16 MFMA GEMM (T1+T2+T3+T4+T5).
//   C = A[M][lda] * Bt[Nn][ldb]^T over k in [kb, kb+kLen)
// 8 waves as 2(M)x4(N); per-wave output 128x64; LDS 128KB =
// 2 buf x {A0,A1,B0,B1} 16KB half-tiles, XOR-swizzled content
// (linear gload_lds dest + inverse-swizzled global source; swizzled reads).
// Stage schedule (deep, 2-buffer-max): at tile t —
//   P1:(t+1).A0  P2:(t+1).A1  P3:(t+2).B0  P4:(t+2).B1, gate vmcnt(4) at P4
//   (leaves (t+2).B* in flight; oldest-drained load is 3-4 phases old).
// WAR: other-buf A regions free after t-1.P3; own-buf B regions free after
// t.P2 (all B reads happen P1/P2). Tail: gate drops to vmcnt(0).
// EPI 0: Hout = relu(acc + bias)  fp16.   EPI 1: atomicAdd(Out, gate*acc).
template <int EPI>
__global__ __launch_bounds__(512, 2) void gemm256_kernel(
    const _Float16* __restrict__ A, const _Float16* __restrict__ Bt,
    const float* __restrict__ bias, const float* __restrict__ gates, int e,
    _Float16* __restrict__ Hout, float* __restrict__ Out, int lda, int ldb,
    int kLen, int Nout) {
  __shared__ _Float16 smem[2][4][8192];  // [buf][A0,A1,B0,B1][16KB]
  const int tid = threadIdx.x, lane = tid & 63, wid = tid >> 6;
  const int wm = wid >> 2, wn = wid & 3;

  // T1: bijective XCD swizzle on the xy-plane (nxy % 8 == 0 always here)
  const int gx = gridDim.x, nxy = gx * gridDim.y;
  const int f = blockIdx.x + gx * blockIdx.y;
  const int sw = (f & 7) * (nxy >> 3) + (f >> 3);
  const int m0 = (sw % gx) * 256, n0 = (sw / gx) * 256;
  const int kb = blockIdx.z * kLen;
  const int NT = kLen >> 6;

  floatx4 acc[8][4] = {};

  auto stage_half = [&](int h) {
    if (h >= 4 * NT) return;
    const int th = h >> 2, j = h & 3, bf = th & 1;
    const int k0 = kb + th * 64;
    const char* gb; int ld, rorig;
    if (j < 2) { gb = (const char*)A;  ld = lda; rorig = m0 + j * 128; }
    else       { gb = (const char*)Bt; ld = ldb; rorig = n0 + (j - 2) * 128; }
    _Float16* lb = &smem[bf][j][0];
#pragma unroll
    for (int i = 0; i < 2; ++i) {
      const int row = (wid * 2 + i) * 8 + (lane >> 3);
      const int gkb = ((lane & 7) * 16) ^ ((row & 7) << 4);  // inverse swizzle
      gload_lds16(gb + ((size_t)(rorig + row) * ld + k0) * 2 + gkb,
                  lb + (wid * 2 + i) * 512 + lane * 8);
    }
  };
  // T2-swizzled fragment reads (2-way bank aliasing = free)
  auto ldA = [&](int bf, int mf, int ks) -> half8 {
    const int row = mf * 16 + (lane & 15);
    const int kb2 = (ks * 64 + ((lane >> 4) << 4)) ^ ((row & 7) << 4);
    return *(const half8*)&smem[bf][wm][(row * 128 + kb2) >> 1];
  };
  auto ldB = [&](int bf, int nf, int ks) -> half8 {
    const int c = wn * 64 + nf * 16 + (lane & 15);
    const int r = c & 127;
    const int kb2 = (ks * 64 + ((lane >> 4) << 4)) ^ ((r & 7) << 4);
    return *(const half8*)&smem[bf][2 + (c >> 7)][(r * 128 + kb2) >> 1];
  };

  // prologue: tile0 all 4 halves + tile1.B0/B1; leave tile1.B* in flight
  stage_half(0); stage_half(1); stage_half(2); stage_half(3);
  stage_half(4 * 1 + 2); stage_half(4 * 1 + 3);
  WAITV(4); SCHED0();
  BARB();

#pragma unroll 1
  for (int t = 0; t < NT; ++t) {
    const int bf = t & 1;
    half8 a[4][2], bh[2][2], bl[2][2];
    // ---- P1: read A m0-3 + B hi; stage (t+1).A0; MFMA m0-3 x n2-3
#pragma unroll
    for (int ks = 0; ks < 2; ++ks) {
#pragma unroll
      for (int m = 0; m < 4; ++m) a[m][ks] = ldA(bf, m, ks);
#pragma unroll
      for (int n = 0; n < 2; ++n) bh[n][ks] = ldB(bf, 2 + n, ks);
    }
    stage_half(4 * (t + 1) + 0);
    BARB(); WAITL0(); SCHED0();
    __builtin_amdgcn_s_setprio(1);
#pragma unroll
    for (int m = 0; m < 4; ++m)
#pragma unroll
      for (int n = 0; n < 2; ++n)
#pragma unroll
        for (int ks = 0; ks < 2; ++ks)
          acc[m][2 + n] = __builtin_amdgcn_mfma_f32_16x16x32_f16(
              a[m][ks], bh[n][ks], acc[m][2 + n], 0, 0, 0);
    __builtin_amdgcn_s_setprio(0);
    BARB();
    // ---- P2: read B lo; stage (t+1).A1; MFMA m0-3 x n0-1
#pragma unroll
    for (int ks = 0; ks < 2; ++ks)
#pragma unroll
      for (int n = 0; n < 2; ++n) bl[n][ks] = ldB(bf, n, ks);
    stage_half(4 * (t + 1) + 1);
    BARB(); WAITL0(); SCHED0();
    __builtin_amdgcn_s_setprio(1);
#pragma unroll
    for (int m = 0; m < 4; ++m)
#pragma unroll
      for (int n = 0; n < 2; ++n)
#pragma unroll
        for (int ks = 0; ks < 2; ++ks)
          acc[m][n] = __builtin_amdgcn_mfma_f32_16x16x32_f16(
              a[m][ks], bl[n][ks], acc[m][n], 0, 0, 0);
    __builtin_amdgcn_s_setprio(0);
    BARB();
    // ---- P3: read A m4-7; stage (t+2).B0 (own-buf B free after P2);
    //          MFMA m4-7 x n2-3
#pragma unroll
    for (int ks = 0; ks < 2; ++ks)
#pragma unroll
      for (int m = 0; m < 4; ++m) a[m][ks] = ldA(bf, 4 + m, ks);
    stage_half(4 * (t + 2) + 2);
    BARB(); WAITL0(); SCHED0();
    __builtin_amdgcn_s_setprio(1);
#pragma unroll
    for (int m = 0; m < 4; ++m)
#pragma unroll
      for (int n = 0; n < 2; ++n)
#pragma unroll
        for (int ks = 0; ks < 2; ++ks)
          acc[4 + m][2 + n] = __builtin_amdgcn_mfma_f32_16x16x32_f16(
              a[m][ks], bh[n][ks], acc[4 + m][2 + n], 0, 0, 0);
    __builtin_amdgcn_s_setprio(0);
    BARB();
    // ---- P4: stage (t+2).B1; MFMA m4-7 x n0-1; counted gate; release
    stage_half(4 * (t + 2) + 3);
    BARB();
    __builtin_amdgcn_s_setprio(1);
#pragma unroll
    for (int m = 0; m < 4; ++m)
#pragma unroll
      for (int n = 0; n < 2; ++n)
#pragma unroll
        for (int ks = 0; ks < 2; ++ks)
          acc[4 + m][n] = __builtin_amdgcn_mfma_f32_16x16x32_f16(
              a[m][ks], bl[n][ks], acc[4 + m][n], 0, 0, 0);
    __builtin_amdgcn_s_setprio(0);
    if (t + 2 < NT) { WAITV(4); } else { WAITV(0); }  // tail: drain A loads
    SCHED0();
    BARB();
  }

  // epilogue: D-frag col = lane&15, row = (lane>>4)*4 + r
#pragma unroll
  for (int mf = 0; mf < 8; ++mf) {
    const int gr0 = m0 + wm * 128 + mf * 16 + ((lane >> 4) << 2);
#pragma unroll
    for (int nf = 0; nf < 4; ++nf) {
      const int gc = n0 + wn * 64 + nf * 16 + (lane & 15);
#pragma unroll
      for (int r = 0; r < 4; ++r) {
        const int gr = gr0 + r;
        if (EPI == 0) {
          const float v = acc[mf][nf][r] + bias[gc];
          Hout[(size_t)gr * Nout + gc] = (_Float16)fmaxf(v, 0.0f);
        } else {
          atomicAdd(Out + (size_t)gr * Nout + gc,
                    gates[(size_t)gr * 8 + e] * acc[mf][nf][r]);
        }
      }
    }
  }
}

// ---------------------------------------------------------------------------
extern "C" void kernel_launch(void* const* d_in, const int* in_sizes, int n_in,
                              void* d_out, int out_size, void* d_ws,
                              size_t ws_size, hipStream_t stream) {
  const float* x  = (const float*)d_in[0];
  const float* gw = (const float*)d_in[1];
  const float* gb = (const float*)d_in[2];
  const float* w1 = (const float*)d_in[3];
  const float* b1 = (const float*)d_in[4];
  const float* w2 = (const float*)d_in[5];
  const float* b2 = (const float*)d_in[6];
  float* out = (float*)d_out;

  const int N = 8192, D = 1024, H = 4096, E = 8;

  char* ws = (char*)d_ws;
  float* gates   = (float*)ws;                                     // 256 KB
  _Float16* x_h  = (_Float16*)(ws + (1ull << 20));                 // 16 MB
  _Float16* w1t  = (_Float16*)(ws + (1ull << 20) + (16ull << 20)); // 8 MB  [H][D]
  _Float16* w2t  = (_Float16*)(ws + (1ull << 20) + (24ull << 20)); // 8 MB  [D][H]
  _Float16* Hbuf = (_Float16*)(ws + (1ull << 20) + (32ull << 20)); // 64 MB [N][H]

  gates_kernel<<<N / 4, 256, 0, stream>>>(x, gw, gb, gates);
  bias_init_kernel<<<N * D / 4 / 256, 256, 0, stream>>>(gates, b2, out);
  cvt_f32_f16_kernel<<<(N * D / 8 + 255) / 256, 256, 0, stream>>>(x, x_h, N * D / 8);

  for (int e = 0; e < E; ++e) {
    transpose_cvt_kernel<<<dim3(H / 32, D / 32), 256, 0, stream>>>(
        w1 + (size_t)e * D * H, w1t, D, H);
    transpose_cvt_kernel<<<dim3(D / 32, H / 32), 256, 0, stream>>>(
        w2 + (size_t)e * H * D, w2t, H, D);
    // GEMM1: [8192,1024] x [4096,1024]^T -> relu(+b1) -> Hbuf fp16 [N][H]
    gemm256_kernel<0><<<dim3(N / 256, H / 256, 1), 512, 0, stream>>>(
        x_h, w1t, b1 + (size_t)e * H, nullptr, e, Hbuf, nullptr, D, D, D, H);
    // GEMM2: [8192,4096] x [1024,4096]^T, split-K x2, gated atomic accumulate
    gemm256_kernel<1><<<dim3(N / 256, D / 256, 2), 512, 0, stream>>>(
        Hbuf, w2t, nullptr, gates, e, nullptr, out, H, H, H / 2, D);
  }
}